// Round 2
// baseline (1542.340 us; speedup 1.0000x reference)
//
#include <hip/hip_runtime.h>
#include <math.h>

// Problem constants
constexpr int BB  = 8;
constexpr int HH  = 256;
constexpr int LL  = 8192;
constexpr int NN  = 16;
constexpr int DTE = 512;
constexpr int SC  = 128;   // chunk length
constexpr int CHN = 64;    // chunks per row (LL/SC)
constexpr int HN  = HH * NN;

constexpr size_t BHL = (size_t)BB * HH * LL;          // 16,777,216 floats
constexpr size_t FN  = (size_t)BB * HH * CHN * NN;    // 2,097,152 floats (per array)

// params region offsets (in floats)
constexpr int OFF_WR  = 0;
constexpr int OFF_WI  = HN;
constexpr int OFF_WSR = 2 * HN;
constexpr int OFF_WSI = 3 * HN;
constexpr int OFF_C0R = 4 * HN;
constexpr int OFF_C0I = 5 * HN;
constexpr int OFF_C1R = 6 * HN;
constexpr int OFF_C1I = 7 * HN;
constexpr int OFF_PT  = 8 * HN;   // part_t (B*H)

__device__ __forceinline__ float gelu_tanh(float x) {
    float x3 = x * x * x;
    float t  = tanhf(0.7978845608028654f * (x + 0.044715f * x3));
    return 0.5f * x * (1.0f + t);
}
__device__ __forceinline__ float sigmoid_(float x) {
    return 1.0f / (1.0f + __expf(-x));
}

// ---------------------------------------------------------------------------
// Setup: discretized SSM params.  w = exp(dt*A); wS = w^S;
// Ceff = 2 * C * (w - 1)/A   (the 2x of "2*Re" folded in)
// ---------------------------------------------------------------------------
__global__ void setup_s4_params(const float* __restrict__ log_dt,
                                const float* __restrict__ A_re,
                                const float* __restrict__ A_im,
                                const float* __restrict__ C_re,
                                const float* __restrict__ C_im,
                                float* __restrict__ P) {
    int idx = blockIdx.x * blockDim.x + threadIdx.x;
    if (idx >= HN) return;
    int h = idx >> 4;
    double dt = exp((double)log_dt[h]);
    double Ar = (double)A_re[idx], Ai = (double)A_im[idx];
    double dr = Ar * dt, di = Ai * dt;          // dtA
    double e1 = exp(dr);
    double wr = e1 * cos(di), wi = e1 * sin(di);
    double eS = exp(dr * SC);
    double wSr = eS * cos(di * SC), wSi = eS * sin(di * SC);
    double d2 = Ar * Ar + Ai * Ai;
    double nr = wr - 1.0, ni = wi;
    double rr = (nr * Ar + ni * Ai) / d2;       // (w-1)/A
    double ri = (ni * Ar - nr * Ai) / d2;
    double c0r = (double)C_re[idx],        c0i = (double)C_im[idx];
    double c1r = (double)C_re[HN + idx],   c1i = (double)C_im[HN + idx];
    P[OFF_WR  + idx] = (float)wr;
    P[OFF_WI  + idx] = (float)wi;
    P[OFF_WSR + idx] = (float)wSr;
    P[OFF_WSI + idx] = (float)wSi;
    P[OFF_C0R + idx] = (float)(2.0 * (c0r * rr - c0i * ri));
    P[OFF_C0I + idx] = (float)(2.0 * (c0r * ri + c0i * rr));
    P[OFF_C1R + idx] = (float)(2.0 * (c1r * rr - c1i * ri));
    P[OFF_C1I + idx] = (float)(2.0 * (c1r * ri + c1i * rr));
}

// part_t[b,h] = emb[b,:] . fc_t_w[h,:] + fc_t_b[h]
__global__ void part_t_kernel(const float* __restrict__ emb,
                              const float* __restrict__ w,
                              const float* __restrict__ bias,
                              float* __restrict__ P) {
    int idx = blockIdx.x * blockDim.x + threadIdx.x;   // B*H
    if (idx >= BB * HH) return;
    int b = idx / HH, h = idx % HH;
    float s = bias[h];
    const float* er = emb + (size_t)b * DTE;
    const float* wr = w + (size_t)h * DTE;
    for (int e = 0; e < DTE; ++e) s = fmaf(er[e], wr[e], s);
    P[OFF_PT + idx] = s;
}

// ---------------------------------------------------------------------------
// TransposedLN over channel dim H per (b,l).  out = s/std*(x-mean+m) [+part_t]
// grid (L/64, B), block 256.  threads: q = tid/64 (h quarter), li = tid%64.
// ---------------------------------------------------------------------------
__global__ void tln_kernel(const float* __restrict__ in, float* __restrict__ out,
                           const float* __restrict__ mptr, const float* __restrict__ sptr,
                           const float* __restrict__ part_t) {
    int b = blockIdx.y;
    int l0 = blockIdx.x * 64;
    int t = threadIdx.x;
    int q = t >> 6, li = t & 63;
    const float* base = in + (size_t)b * HH * LL + l0 + li;
    float sum = 0.f, sq = 0.f;
    for (int i = 0; i < 64; ++i) {
        float v = base[(size_t)(q * 64 + i) * LL];
        sum += v; sq = fmaf(v, v, sq);
    }
    __shared__ float rs[4][64], rq[4][64], meanS[64], scaleS[64];
    rs[q][li] = sum; rq[q][li] = sq;
    __syncthreads();
    if (q == 0) {
        float s  = rs[0][li] + rs[1][li] + rs[2][li] + rs[3][li];
        float s2 = rq[0][li] + rq[1][li] + rq[2][li] + rq[3][li];
        float mean = s * (1.f / 256.f);
        float var  = fmaxf(s2 * (1.f / 256.f) - mean * mean, 0.f);
        meanS[li]  = mean;
        scaleS[li] = sptr[0] / sqrtf(var);
    }
    __syncthreads();
    float mean = meanS[li], scale = scaleS[li], m = mptr[0];
    float* ob = out + (size_t)b * HH * LL + l0 + li;
    for (int i = 0; i < 64; ++i) {
        int h = q * 64 + i;
        float v = base[(size_t)h * LL];
        float y = scale * (v - mean + m);
        if (part_t) y += part_t[b * HH + h];
        ob[(size_t)h * LL] = y;
    }
}

// ---------------------------------------------------------------------------
// Scan pass 1: per-(b,h,chunk) local finals, fwd and bwd, all 16 modes.
// Ffwd[c] = sum_j u[cS+j] w^(S-1-j) ; Fbwd[c] = sum_j u[cS+j] w^j
// ---------------------------------------------------------------------------
__global__ void scan_finals_kernel(const float* __restrict__ u, const float* __restrict__ P,
                                   float* __restrict__ Ffr, float* __restrict__ Ffi,
                                   float* __restrict__ Fbr, float* __restrict__ Fbi) {
    int idx = blockIdx.x * 256 + threadIdx.x;      // B*H*CHN
    int chunk = idx & (CHN - 1);
    int bh = idx / CHN;
    int h = bh & (HH - 1);
    float wr[NN], wi[NN];
    #pragma unroll
    for (int n = 0; n < NN; ++n) { wr[n] = P[OFF_WR + h * NN + n]; wi[n] = P[OFF_WI + h * NN + n]; }
    const float4* ub = (const float4*)(u + (size_t)bh * LL + (size_t)chunk * SC);
    float fr[NN], fi[NN];
    #pragma unroll
    for (int n = 0; n < NN; ++n) { fr[n] = 0.f; fi[n] = 0.f; }
    for (int j4 = 0; j4 < SC / 4; ++j4) {
        float4 uu = ub[j4];
        #pragma unroll
        for (int e = 0; e < 4; ++e) {
            float uv = (&uu.x)[e];
            #pragma unroll
            for (int n = 0; n < NN; ++n) {
                float nr = fmaf(wr[n], fr[n], fmaf(-wi[n], fi[n], uv));
                float ni = fmaf(wr[n], fi[n], wi[n] * fr[n]);
                fr[n] = nr; fi[n] = ni;
            }
        }
    }
    size_t fo = (size_t)idx * NN;
    #pragma unroll
    for (int n = 0; n < NN; ++n) { Ffr[fo + n] = fr[n]; Ffi[fo + n] = fi[n]; }
    #pragma unroll
    for (int n = 0; n < NN; ++n) { fr[n] = 0.f; fi[n] = 0.f; }
    for (int j4 = SC / 4 - 1; j4 >= 0; --j4) {
        float4 uu = ub[j4];
        #pragma unroll
        for (int e = 3; e >= 0; --e) {
            float uv = (&uu.x)[e];
            #pragma unroll
            for (int n = 0; n < NN; ++n) {
                float nr = fmaf(wr[n], fr[n], fmaf(-wi[n], fi[n], uv));
                float ni = fmaf(wr[n], fi[n], wi[n] * fr[n]);
                fr[n] = nr; fi[n] = ni;
            }
        }
    }
    #pragma unroll
    for (int n = 0; n < NN; ++n) { Fbr[fo + n] = fr[n]; Fbi[fo + n] = fi[n]; }
}

// ---------------------------------------------------------------------------
// Scan pass 2: serial prefix over CHN chunks per (b,h,n), IN PLACE:
// F arrays are read then overwritten with the incoming-carry values.
// After this kernel: Ff* holds H (fwd state entering chunk c),
//                    Fb* holds Z (bwd state entering chunk c from the right).
// ---------------------------------------------------------------------------
__global__ void scan_carry_kernel(const float* __restrict__ P,
                                  float* Ffr, float* Ffi,
                                  float* Fbr, float* Fbi) {
    int idx = blockIdx.x * 256 + threadIdx.x;      // B*H*N
    if (idx >= BB * HH * NN) return;
    int n = idx & (NN - 1);
    int bh = idx >> 4;
    int h = bh & (HH - 1);
    float wSr = P[OFF_WSR + h * NN + n], wSi = P[OFF_WSI + h * NN + n];
    float cr = 0.f, ci = 0.f;
    for (int c = 0; c < CHN; ++c) {
        size_t o = ((size_t)bh * CHN + c) * NN + n;
        float fr = Ffr[o], fi = Ffi[o];
        Ffr[o] = cr; Ffi[o] = ci;
        float nr = fmaf(wSr, cr, fmaf(-wSi, ci, fr));
        float ni = fmaf(wSr, ci, fmaf(wSi, cr, fi));
        cr = nr; ci = ni;
    }
    cr = 0.f; ci = 0.f;
    for (int c = CHN - 1; c >= 0; --c) {
        size_t o = ((size_t)bh * CHN + c) * NN + n;
        float fr = Fbr[o], fi = Fbi[o];
        Fbr[o] = cr; Fbi[o] = ci;
        float nr = fmaf(wSr, cr, fmaf(-wSi, ci, fr));
        float ni = fmaf(wSr, ci, fmaf(wSi, cr, fi));
        cr = nr; ci = ni;
    }
}

// Scan pass 3a: forward outputs.  yf[t] = sum_n Re(C0 * h[t])
__global__ void scan_fwd_kernel(const float* __restrict__ u, const float* __restrict__ P,
                                const float* __restrict__ Hcr, const float* __restrict__ Hci,
                                float* __restrict__ yf) {
    int idx = blockIdx.x * 256 + threadIdx.x;
    int chunk = idx & (CHN - 1);
    int bh = idx / CHN;
    int h = bh & (HH - 1);
    float wr[NN], wi[NN], cr[NN], ci[NN], sr[NN], si[NN];
    size_t co = (size_t)idx * NN;
    #pragma unroll
    for (int n = 0; n < NN; ++n) {
        wr[n] = P[OFF_WR + h * NN + n];  wi[n] = P[OFF_WI + h * NN + n];
        cr[n] = P[OFF_C0R + h * NN + n]; ci[n] = P[OFF_C0I + h * NN + n];
        sr[n] = Hcr[co + n];             si[n] = Hci[co + n];
    }
    const float4* ub = (const float4*)(u + (size_t)bh * LL + (size_t)chunk * SC);
    float4* yo = (float4*)(yf + (size_t)bh * LL + (size_t)chunk * SC);
    for (int j4 = 0; j4 < SC / 4; ++j4) {
        float4 uu = ub[j4], oo;
        #pragma unroll
        for (int e = 0; e < 4; ++e) {
            float uv = (&uu.x)[e];
            float acc = 0.f;
            #pragma unroll
            for (int n = 0; n < NN; ++n) {
                float nr = fmaf(wr[n], sr[n], fmaf(-wi[n], si[n], uv));
                float ni = fmaf(wr[n], si[n], wi[n] * sr[n]);
                sr[n] = nr; si[n] = ni;
                acc = fmaf(cr[n], nr, fmaf(-ci[n], ni, acc));
            }
            (&oo.x)[e] = acc;
        }
        yo[j4] = oo;
    }
}

// Scan pass 3b: backward outputs + combine: ys = gelu(yf + yb + u*D)
// NOTE: ys aliases u (in-place, same-index read-before-write) — no __restrict__.
__global__ void scan_bwd_kernel(const float* u, const float* __restrict__ P,
                                const float* __restrict__ Zcr, const float* __restrict__ Zci,
                                const float* __restrict__ yf, const float* __restrict__ Dp,
                                float* ys) {
    int idx = blockIdx.x * 256 + threadIdx.x;
    int chunk = idx & (CHN - 1);
    int bh = idx / CHN;
    int h = bh & (HH - 1);
    float wr[NN], wi[NN], cr[NN], ci[NN], zr[NN], zi[NN];
    size_t co = (size_t)idx * NN;
    #pragma unroll
    for (int n = 0; n < NN; ++n) {
        wr[n] = P[OFF_WR + h * NN + n];  wi[n] = P[OFF_WI + h * NN + n];
        cr[n] = P[OFF_C1R + h * NN + n]; ci[n] = P[OFF_C1I + h * NN + n];
        zr[n] = Zcr[co + n];             zi[n] = Zci[co + n];
    }
    float Dh = Dp[h];
    const float4* ub = (const float4*)(u + (size_t)bh * LL + (size_t)chunk * SC);
    const float4* fb = (const float4*)(yf + (size_t)bh * LL + (size_t)chunk * SC);
    float4* yo = (float4*)(ys + (size_t)bh * LL + (size_t)chunk * SC);
    for (int j4 = SC / 4 - 1; j4 >= 0; --j4) {
        float4 uu = ub[j4], ff = fb[j4], oo;
        #pragma unroll
        for (int e = 3; e >= 0; --e) {
            float uv = (&uu.x)[e];
            // z currently holds z[t+1]; yb[t] = sum_n Re(C1 . z[t+1])
            float acc = 0.f;
            #pragma unroll
            for (int n = 0; n < NN; ++n)
                acc = fmaf(cr[n], zr[n], fmaf(-ci[n], zi[n], acc));
            float g = (&ff.x)[e] + acc + uv * Dh;
            (&oo.x)[e] = gelu_tanh(g);
            #pragma unroll
            for (int n = 0; n < NN; ++n) {   // z[t] = u[t] + w*z[t+1]
                float nr = fmaf(wr[n], zr[n], fmaf(-wi[n], zi[n], uv));
                float ni = fmaf(wr[n], zi[n], wi[n] * zr[n]);
                zr[n] = nr; zi[n] = ni;
            }
        }
        yo[j4] = oo;
    }
}

// ---------------------------------------------------------------------------
// GEMM 1: z = out_w(512x256) @ ys4 + out_b ; GLU ; + x residual  -> res
// grid (L/64, 4, B), block 256, per-thread 4x4, two accumulator sets.
// ---------------------------------------------------------------------------
__global__ void gemm_glu_kernel(const float* __restrict__ X, const float* __restrict__ W,
                                const float* __restrict__ bias, const float* __restrict__ xres,
                                float* __restrict__ out) {
    __shared__ __align__(16) float Xs[32][68];
    __shared__ __align__(16) float W0s[32][68];
    __shared__ __align__(16) float W1s[32][68];
    int b = blockIdx.z;
    int l0 = blockIdx.x * 64;
    int c0 = blockIdx.y * 64;
    int t = threadIdx.x, tx = t & 15, ty = t >> 4;
    float acc0[4][4] = {}, acc1[4][4] = {};
    const float* Xb = X + (size_t)b * HH * LL;
    for (int k0 = 0; k0 < HH; k0 += 32) {
        #pragma unroll
        for (int i = 0; i < 8; ++i) {
            int idx = t + i * 256, k = idx >> 6, l = idx & 63;
            Xs[k][l] = Xb[(size_t)(k0 + k) * LL + l0 + l];
        }
        {
            int o = t >> 2, kk = (t & 3) * 8;
            const float* wp0 = W + (size_t)(c0 + o) * HH + k0 + kk;
            const float* wp1 = W + (size_t)(c0 + 256 + o) * HH + k0 + kk;
            #pragma unroll
            for (int j = 0; j < 8; ++j) { W0s[kk + j][o] = wp0[j]; W1s[kk + j][o] = wp1[j]; }
        }
        __syncthreads();
        #pragma unroll
        for (int k = 0; k < 32; ++k) {
            float4 xv = *(const float4*)&Xs[k][tx * 4];
            float4 w0 = *(const float4*)&W0s[k][ty * 4];
            float4 w1 = *(const float4*)&W1s[k][ty * 4];
            const float* xp = &xv.x; const float* p0 = &w0.x; const float* p1 = &w1.x;
            #pragma unroll
            for (int i = 0; i < 4; ++i)
                #pragma unroll
                for (int j = 0; j < 4; ++j) {
                    acc0[i][j] = fmaf(p0[i], xp[j], acc0[i][j]);
                    acc1[i][j] = fmaf(p1[i], xp[j], acc1[i][j]);
                }
        }
        __syncthreads();
    }
    #pragma unroll
    for (int i = 0; i < 4; ++i) {
        int c = c0 + ty * 4 + i;
        float b0 = bias[c], b1 = bias[c + 256];
        float4 xr = *(const float4*)&xres[((size_t)b * HH + c) * LL + l0 + tx * 4];
        float4 ov;
        #pragma unroll
        for (int j = 0; j < 4; ++j) {
            float z0 = acc0[i][j] + b0;
            float z1 = acc1[i][j] + b1;
            (&ov.x)[j] = z0 * sigmoid_(z1) + (&xr.x)[j];
        }
        *(float4*)&out[((size_t)b * HH + c) * LL + l0 + tx * 4] = ov;
    }
}

// Generic GEMM: out[b,o,l] = act(sum_k W[o,k] X[b,k,l] + bias[o]) (+resid)
// KV = k extent, WLD = W row stride (W may be pre-offset for column slices).
// ACT: 1 = gelu (ff1 halves), 0 = none + residual add (ff2 partial passes;
//      resid may alias out — same-index read-before-write; bias may be null).
template <int KV, int WLD, int ACT>
__global__ void gemm_kernel(const float* __restrict__ X, const float* __restrict__ W,
                            const float* bias, const float* resid,
                            float* out) {
    __shared__ __align__(16) float Xs[32][68];
    __shared__ __align__(16) float Ws[32][68];
    int b = blockIdx.z;
    int l0 = blockIdx.x * 64;
    int o0 = blockIdx.y * 64;
    int O = gridDim.y * 64;
    int t = threadIdx.x, tx = t & 15, ty = t >> 4;
    float acc[4][4] = {};
    const float* Xb = X + (size_t)b * KV * LL;
    for (int k0 = 0; k0 < KV; k0 += 32) {
        #pragma unroll
        for (int i = 0; i < 8; ++i) {
            int idx = t + i * 256, k = idx >> 6, l = idx & 63;
            Xs[k][l] = Xb[(size_t)(k0 + k) * LL + l0 + l];
        }
        {
            int o = t >> 2, kk = (t & 3) * 8;
            const float* wp = W + (size_t)(o0 + o) * WLD + k0 + kk;
            #pragma unroll
            for (int j = 0; j < 8; ++j) Ws[kk + j][o] = wp[j];
        }
        __syncthreads();
        #pragma unroll
        for (int k = 0; k < 32; ++k) {
            float4 xv = *(const float4*)&Xs[k][tx * 4];
            float4 wv = *(const float4*)&Ws[k][ty * 4];
            const float* xp = &xv.x; const float* wp = &wv.x;
            #pragma unroll
            for (int i = 0; i < 4; ++i)
                #pragma unroll
                for (int j = 0; j < 4; ++j)
                    acc[i][j] = fmaf(wp[i], xp[j], acc[i][j]);
        }
        __syncthreads();
    }
    #pragma unroll
    for (int i = 0; i < 4; ++i) {
        int o = o0 + ty * 4 + i;
        float bv = bias ? bias[o] : 0.f;
        float4 ov;
        if (ACT == 0) {
            float4 rv = *(const float4*)&resid[((size_t)b * O + o) * LL + l0 + tx * 4];
            #pragma unroll
            for (int j = 0; j < 4; ++j) (&ov.x)[j] = acc[i][j] + bv + (&rv.x)[j];
        } else {
            #pragma unroll
            for (int j = 0; j < 4; ++j) (&ov.x)[j] = gelu_tanh(acc[i][j] + bv);
        }
        *(float4*)&out[((size_t)b * O + o) * LL + l0 + tx * 4] = ov;
    }
}

// ---------------------------------------------------------------------------
extern "C" void kernel_launch(void* const* d_in, const int* in_sizes, int n_in,
                              void* d_out, int out_size, void* d_ws, size_t ws_size,
                              hipStream_t stream) {
    (void)in_sizes; (void)n_in; (void)out_size; (void)ws_size;
    const float* x      = (const float*)d_in[0];
    const float* emb    = (const float*)d_in[1];
    const float* fc_t_w = (const float*)d_in[2];
    const float* fc_t_b = (const float*)d_in[3];
    const float* log_dt = (const float*)d_in[4];
    const float* A_re   = (const float*)d_in[5];
    const float* A_im   = (const float*)d_in[6];
    const float* C_re   = (const float*)d_in[7];
    const float* C_im   = (const float*)d_in[8];
    const float* Dp     = (const float*)d_in[9];
    const float* out_w  = (const float*)d_in[10];
    const float* out_b  = (const float*)d_in[11];
    const float* n1_m   = (const float*)d_in[12];
    const float* n1_s   = (const float*)d_in[13];
    const float* n2_m   = (const float*)d_in[14];
    const float* n2_s   = (const float*)d_in[15];
    const float* ff_w1  = (const float*)d_in[16];
    const float* ff_b1  = (const float*)d_in[17];
    const float* ff_w2  = (const float*)d_in[18];
    const float* ff_b2  = (const float*)d_in[19];
    float* outp = (float*)d_out;

    // Workspace: exactly 2*BHL floats = 128 MiB.
    //   region A [0, BHL):        u (TLN1 out) -> ys4 (in place) -> t2 (TLN2 out)
    //   region B [BHL, 2*BHL):    scans: Ff/Fb (4*FN = BHL/2) + params P in the
    //                             upper half; FF stage: h half (BHL, overwrites P
    //                             which is dead by then)
    //   yf lives in d_out (dead before res is written there); res lives in d_out.
    float* wsf  = (float*)d_ws;
    float* u    = wsf;                      // region A
    float* regB = wsf + BHL;                // region B
    float* Ffr = regB;          float* Ffi = regB + FN;
    float* Fbr = regB + 2 * FN; float* Fbi = regB + 3 * FN;
    float* P    = regB + 4 * FN;            // 34,816 floats, fits in upper half
    float* yfb  = outp;                     // forward-scan output buffer
    float* hbuf = regB;                     // FF hidden half (B,256,L) = BHL floats

    setup_s4_params<<<16, 256, 0, stream>>>(log_dt, A_re, A_im, C_re, C_im, P);
    part_t_kernel<<<8, 256, 0, stream>>>(emb, fc_t_w, fc_t_b, P);

    // u = TLN1(x) + part_t
    tln_kernel<<<dim3(LL / 64, BB), 256, 0, stream>>>(x, u, n1_m, n1_s, P + OFF_PT);

    // bidirectional diagonal SSM scan (exact equivalent of the FFT conv)
    scan_finals_kernel<<<512, 256, 0, stream>>>(u, P, Ffr, Ffi, Fbr, Fbi);
    scan_carry_kernel<<<128, 256, 0, stream>>>(P, Ffr, Ffi, Fbr, Fbi);  // in place: F -> H/Z
    scan_fwd_kernel<<<512, 256, 0, stream>>>(u, P, Ffr, Ffi, yfb);
    scan_bwd_kernel<<<512, 256, 0, stream>>>(u, P, Fbr, Fbi, yfb, Dp, u);  // ys4 over u

    // res = x + GLU(out_w @ ys4 + out_b)   -> d_out (overwrites dead yf)
    gemm_glu_kernel<<<dim3(LL / 64, 4, BB), 256, 0, stream>>>(u, out_w, out_b, x, outp);

    // t2 = TLN2(res)  (into region A, over dead ys4)
    tln_kernel<<<dim3(LL / 64, BB), 256, 0, stream>>>(outp, u, n2_m, n2_s, nullptr);

    // FF in two 256-channel halves (h half fits in region B):
    // h1 = gelu(ff_w1[0:256] @ t2 + ff_b1[0:256])
    gemm_kernel<256, 256, 1><<<dim3(LL / 64, 4, BB), 256, 0, stream>>>(u, ff_w1, ff_b1, nullptr, hbuf);
    // out = res + ff_w2[:, 0:256] @ h1 + ff_b2   (in place over d_out)
    gemm_kernel<256, 512, 0><<<dim3(LL / 64, 4, BB), 256, 0, stream>>>(hbuf, ff_w2, ff_b2, outp, outp);
    // h2 = gelu(ff_w1[256:512] @ t2 + ff_b1[256:512])
    gemm_kernel<256, 256, 1><<<dim3(LL / 64, 4, BB), 256, 0, stream>>>(u, ff_w1 + 256 * 256, ff_b1 + 256, nullptr, hbuf);
    // out += ff_w2[:, 256:512] @ h2   (no bias this pass)
    gemm_kernel<256, 512, 0><<<dim3(LL / 64, 4, BB), 256, 0, stream>>>(hbuf, ff_w2 + 256, nullptr, outp, outp);
}

// Round 3
// 1159.669 us; speedup vs baseline: 1.3300x; 1.3300x over previous
//
#include <hip/hip_runtime.h>
#include <hip/hip_bf16.h>
#include <math.h>

// Problem constants
constexpr int BB  = 8;
constexpr int HH  = 256;
constexpr int LL  = 8192;
constexpr int NN  = 16;
constexpr int DTE = 512;
constexpr int SC  = 128;   // chunk length
constexpr int CHN = 64;    // chunks per row (LL/SC)
constexpr int HN  = HH * NN;

constexpr size_t BHL = (size_t)BB * HH * LL;          // 16,777,216 floats

// params region offsets (in floats)
constexpr int OFF_WR  = 0;
constexpr int OFF_WI  = HN;
constexpr int OFF_WSR = 2 * HN;
constexpr int OFF_WSI = 3 * HN;
constexpr int OFF_C0R = 4 * HN;
constexpr int OFF_C0I = 5 * HN;
constexpr int OFF_C1R = 6 * HN;
constexpr int OFF_C1I = 7 * HN;
constexpr int OFF_PT  = 8 * HN;   // part_t (B*H)

__device__ __forceinline__ float gelu_tanh(float x) {
    // x * sigmoid(2*0.7978845608*(x + 0.044715 x^3))  == tanh-form gelu
    float x3 = x * x * x;
    float y = 1.5957691216057308f * x + 0.07135481627767453f * x3;
    return x / (1.0f + __expf(-y));
}
__device__ __forceinline__ float sigmoid_(float x) {
    return 1.0f / (1.0f + __expf(-x));
}
__device__ __forceinline__ __hip_bfloat16 f2b(float x) { return __float2bfloat16(x); }
__device__ __forceinline__ float b2f(__hip_bfloat16 x) { return __bfloat162float(x); }

// ---------------------------------------------------------------------------
// Setup: discretized SSM params.  w = exp(dt*A); wS = w^SC;
// Ceff = 2 * C * (w - 1)/A   (the 2x of "2*Re" folded in)
// ---------------------------------------------------------------------------
__global__ void setup_s4_params(const float* __restrict__ log_dt,
                                const float* __restrict__ A_re,
                                const float* __restrict__ A_im,
                                const float* __restrict__ C_re,
                                const float* __restrict__ C_im,
                                float* __restrict__ P) {
    int idx = blockIdx.x * blockDim.x + threadIdx.x;
    if (idx >= HN) return;
    int h = idx >> 4;
    double dt = exp((double)log_dt[h]);
    double Ar = (double)A_re[idx], Ai = (double)A_im[idx];
    double dr = Ar * dt, di = Ai * dt;          // dtA
    double e1 = exp(dr);
    double wr = e1 * cos(di), wi = e1 * sin(di);
    double eS = exp(dr * SC);
    double wSr = eS * cos(di * SC), wSi = eS * sin(di * SC);
    double d2 = Ar * Ar + Ai * Ai;
    double nr = wr - 1.0, ni = wi;
    double rr = (nr * Ar + ni * Ai) / d2;       // (w-1)/A
    double ri = (ni * Ar - nr * Ai) / d2;
    double c0r = (double)C_re[idx],        c0i = (double)C_im[idx];
    double c1r = (double)C_re[HN + idx],   c1i = (double)C_im[HN + idx];
    P[OFF_WR  + idx] = (float)wr;
    P[OFF_WI  + idx] = (float)wi;
    P[OFF_WSR + idx] = (float)wSr;
    P[OFF_WSI + idx] = (float)wSi;
    P[OFF_C0R + idx] = (float)(2.0 * (c0r * rr - c0i * ri));
    P[OFF_C0I + idx] = (float)(2.0 * (c0r * ri + c0i * rr));
    P[OFF_C1R + idx] = (float)(2.0 * (c1r * rr - c1i * ri));
    P[OFF_C1I + idx] = (float)(2.0 * (c1r * ri + c1i * rr));
}

// part_t[b,h] = emb[b,:] . fc_t_w[h,:] + fc_t_b[h]
__global__ void part_t_kernel(const float* __restrict__ emb,
                              const float* __restrict__ w,
                              const float* __restrict__ bias,
                              float* __restrict__ P) {
    int idx = blockIdx.x * blockDim.x + threadIdx.x;   // B*H
    if (idx >= BB * HH) return;
    int b = idx / HH, h = idx % HH;
    float s = bias[h];
    const float* er = emb + (size_t)b * DTE;
    const float* wr = w + (size_t)h * DTE;
    for (int e = 0; e < DTE; ++e) s = fmaf(er[e], wr[e], s);
    P[OFF_PT + idx] = s;
}

// ---------------------------------------------------------------------------
// TransposedLN over channel dim H per (b,l).  out = s/std*(x-mean+m) [+part_t]
// ---------------------------------------------------------------------------
__global__ void tln_kernel(const float* __restrict__ in, float* __restrict__ out,
                           const float* __restrict__ mptr, const float* __restrict__ sptr,
                           const float* __restrict__ part_t) {
    int b = blockIdx.y;
    int l0 = blockIdx.x * 64;
    int t = threadIdx.x;
    int q = t >> 6, li = t & 63;
    const float* base = in + (size_t)b * HH * LL + l0 + li;
    float sum = 0.f, sq = 0.f;
    for (int i = 0; i < 64; ++i) {
        float v = base[(size_t)(q * 64 + i) * LL];
        sum += v; sq = fmaf(v, v, sq);
    }
    __shared__ float rs[4][64], rq[4][64], meanS[64], scaleS[64];
    rs[q][li] = sum; rq[q][li] = sq;
    __syncthreads();
    if (q == 0) {
        float s  = rs[0][li] + rs[1][li] + rs[2][li] + rs[3][li];
        float s2 = rq[0][li] + rq[1][li] + rq[2][li] + rq[3][li];
        float mean = s * (1.f / 256.f);
        float var  = fmaxf(s2 * (1.f / 256.f) - mean * mean, 0.f);
        meanS[li]  = mean;
        scaleS[li] = sptr[0] / sqrtf(var);
    }
    __syncthreads();
    float mean = meanS[li], scale = scaleS[li], m = mptr[0];
    float* ob = out + (size_t)b * HH * LL + l0 + li;
    for (int i = 0; i < 64; ++i) {
        int h = q * 64 + i;
        float v = base[(size_t)h * LL];
        float y = scale * (v - mean + m);
        if (part_t) y += part_t[b * HH + h];
        ob[(size_t)h * LL] = y;
    }
}

// ---------------------------------------------------------------------------
// Fused bidirectional SSM scan: one block per (b,h) row.
//   phase 1: coalesced load row -> LDS (chunk stride 132, 16B-aligned)
//   phase 2: per-chunk finals fwd/bwd (256 thr = 64 chunks x 2 dir x 2 mode-halves)
//   phase 3: carry prefix across 64 chunks (32 thr, in place over finals)
//   stage A: fwd emits yf[0..63], bwd emits yb[64..127] (bf16, LDS)
//   stage B: fwd combines j=64..127, bwd combines j=0..63 -> gelu -> su in place
//   phase 6: coalesced store row.
// ys aliases u (in place).
// ---------------------------------------------------------------------------
constexpr int SUP  = 132;   // su / ybuf chunk stride (pad 4 -> 8-way max aliasing)
constexpr int FINP = 130;   // fin per-(dir,n) stride in bf16 elems (65 complex slots)

__global__ __launch_bounds__(256, 2) void scan_fused(
    const float* __restrict__ uIn, const float* __restrict__ P,
    const float* __restrict__ Dp, float* __restrict__ ys)
{
    __shared__ float          su[64 * SUP];           // 33,792 B
    __shared__ __hip_bfloat16 ybuf[64 * SUP];         // 16,896 B
    __shared__ __hip_bfloat16 fin[2 * NN * FINP];     //  8,320 B

    const int bh  = blockIdx.x;
    const int h   = bh & (HH - 1);
    const int tid = threadIdx.x;
    const float* urow = uIn + (size_t)bh * LL;
    float* yrow = ys + (size_t)bh * LL;

    // ---- phase 1: load row ----
    {
        const float4* u4 = (const float4*)urow;
        #pragma unroll
        for (int i = 0; i < 8; ++i) {
            int e4 = tid + i * 256;
            float4 v = u4[e4];
            int g = e4 << 2;
            int c = g >> 7, j = g & 127;
            *(float4*)&su[c * SUP + j] = v;
        }
    }
    __syncthreads();

    // ---- phase 2: chunk finals (8 modes per thread) ----
    {
        const int c   = tid & 63;
        const int dir = (tid >> 6) & 1;
        const int nb  = (tid >> 7) * 8;
        float wr8[8], wi8[8], fr[8], fi[8];
        #pragma unroll
        for (int k = 0; k < 8; ++k) {
            wr8[k] = P[OFF_WR + h * NN + nb + k];
            wi8[k] = P[OFF_WI + h * NN + nb + k];
            fr[k] = 0.f; fi[k] = 0.f;
        }
        const float* sc = &su[c * SUP];
        if (dir == 0) {
            for (int j = 0; j < 128; ++j) {
                float uv = sc[j];
                #pragma unroll
                for (int k = 0; k < 8; ++k) {
                    float nr = fmaf(wr8[k], fr[k], fmaf(-wi8[k], fi[k], uv));
                    float ni = fmaf(wr8[k], fi[k], wi8[k] * fr[k]);
                    fr[k] = nr; fi[k] = ni;
                }
            }
        } else {
            for (int j = 127; j >= 0; --j) {
                float uv = sc[j];
                #pragma unroll
                for (int k = 0; k < 8; ++k) {
                    float nr = fmaf(wr8[k], fr[k], fmaf(-wi8[k], fi[k], uv));
                    float ni = fmaf(wr8[k], fi[k], wi8[k] * fr[k]);
                    fr[k] = nr; fi[k] = ni;
                }
            }
        }
        #pragma unroll
        for (int k = 0; k < 8; ++k) {
            int n = nb + k;
            __hip_bfloat16* fp = &fin[(dir * NN + n) * FINP + 2 * c];
            fp[0] = f2b(fr[k]); fp[1] = f2b(fi[k]);
        }
    }
    __syncthreads();

    // ---- phase 3: carry prefix over chunks, in place ----
    if (tid < 32) {
        const int dir = tid >> 4, n = tid & 15;
        float wSr = P[OFF_WSR + h * NN + n], wSi = P[OFF_WSI + h * NN + n];
        __hip_bfloat16* fb = &fin[(dir * NN + n) * FINP];
        float cr = 0.f, ci = 0.f;
        if (dir == 0) {
            for (int c = 0; c < CHN; ++c) {
                float fr = b2f(fb[2 * c]), fi = b2f(fb[2 * c + 1]);
                fb[2 * c] = f2b(cr); fb[2 * c + 1] = f2b(ci);
                float nr = fmaf(wSr, cr, fmaf(-wSi, ci, fr));
                float ni = fmaf(wSr, ci, fmaf(wSi, cr, fi));
                cr = nr; ci = ni;
            }
        } else {
            for (int c = CHN - 1; c >= 0; --c) {
                float fr = b2f(fb[2 * c]), fi = b2f(fb[2 * c + 1]);
                fb[2 * c] = f2b(cr); fb[2 * c + 1] = f2b(ci);
                float nr = fmaf(wSr, cr, fmaf(-wSi, ci, fr));
                float ni = fmaf(wSr, ci, fmaf(wSi, cr, fi));
                cr = nr; ci = ni;
            }
        }
    }
    __syncthreads();

    // ---- directional scans (threads 0..127; role 0 = fwd, 1 = bwd) ----
    float wr[NN], wi[NN], cr[NN], ci[NN], sr[NN], si[NN];
    float ucur = 0.f;
    const int role = (tid >> 6) & 1;
    const int c = tid & 63;
    float* sc = &su[c * SUP];
    __hip_bfloat16* yc = &ybuf[c * SUP];
    const float Dh = Dp[h];

    if (tid < 128) {
        const int cO = role ? OFF_C1R : OFF_C0R;
        const int cI = role ? OFF_C1I : OFF_C0I;
        #pragma unroll
        for (int n = 0; n < NN; ++n) {
            wr[n] = P[OFF_WR + h * NN + n]; wi[n] = P[OFF_WI + h * NN + n];
            cr[n] = P[cO + h * NN + n];     ci[n] = P[cI + h * NN + n];
            const __hip_bfloat16* fp = &fin[(role * NN + n) * FINP + 2 * c];
            sr[n] = b2f(fp[0]); si[n] = b2f(fp[1]);
        }
        if (role == 0) {
            // fwd stage A: j = 0..63, store yf -> ybuf
            for (int j = 0; j < 64; ++j) {
                float uv = sc[j];
                float acc = 0.f;
                #pragma unroll
                for (int n = 0; n < NN; ++n) {
                    float nr = fmaf(wr[n], sr[n], fmaf(-wi[n], si[n], uv));
                    float ni = fmaf(wr[n], si[n], wi[n] * sr[n]);
                    sr[n] = nr; si[n] = ni;
                    acc = fmaf(cr[n], nr, fmaf(-ci[n], ni, acc));
                }
                yc[j] = f2b(acc);
            }
        } else {
            // bwd stage A: y[127] = C.z[128]; then t = 127..65 storing y[t-1]
            {
                float acc = 0.f;
                #pragma unroll
                for (int n = 0; n < NN; ++n)
                    acc = fmaf(cr[n], sr[n], fmaf(-ci[n], si[n], acc));
                yc[127] = f2b(acc);
            }
            for (int t = 127; t >= 65; --t) {
                float uv = sc[t];
                float acc = 0.f;
                #pragma unroll
                for (int n = 0; n < NN; ++n) {
                    float nr = fmaf(wr[n], sr[n], fmaf(-wi[n], si[n], uv));
                    float ni = fmaf(wr[n], si[n], wi[n] * sr[n]);
                    sr[n] = nr; si[n] = ni;           // z[t]
                    acc = fmaf(cr[n], nr, fmaf(-ci[n], ni, acc));  // y[t-1]
                }
                yc[t - 1] = f2b(acc);
            }
            ucur = sc[64];   // u[64], read before fwd overwrites in stage B
        }
    }
    __syncthreads();
    if (tid < 128) {
        if (role == 0) {
            // fwd stage B: j = 64..127, combine with yb half, write su in place
            for (int j = 64; j < 128; ++j) {
                float uv = sc[j];
                float acc = 0.f;
                #pragma unroll
                for (int n = 0; n < NN; ++n) {
                    float nr = fmaf(wr[n], sr[n], fmaf(-wi[n], si[n], uv));
                    float ni = fmaf(wr[n], si[n], wi[n] * sr[n]);
                    sr[n] = nr; si[n] = ni;
                    acc = fmaf(cr[n], nr, fmaf(-ci[n], ni, acc));
                }
                float tot = acc + b2f(yc[j]) + uv * Dh;
                sc[j] = gelu_tanh(tot);
            }
        } else {
            // bwd stage B: t = 64..1; state = z[65] on entry, ucur = u[64]
            for (int t = 64; t >= 1; --t) {
                float acc = 0.f;
                #pragma unroll
                for (int n = 0; n < NN; ++n) {
                    float nr = fmaf(wr[n], sr[n], fmaf(-wi[n], si[n], ucur));
                    float ni = fmaf(wr[n], si[n], wi[n] * sr[n]);
                    sr[n] = nr; si[n] = ni;           // z[t]
                    acc = fmaf(cr[n], nr, fmaf(-ci[n], ni, acc));  // y[t-1]
                }
                float un = sc[t - 1];
                float tot = acc + b2f(yc[t - 1]) + un * Dh;
                sc[t - 1] = gelu_tanh(tot);
                ucur = un;
            }
        }
    }
    __syncthreads();

    // ---- phase 6: store row ----
    {
        #pragma unroll
        for (int i = 0; i < 8; ++i) {
            int e4 = tid + i * 256;
            int g = e4 << 2;
            int c2 = g >> 7, j = g & 127;
            float4 v = *(const float4*)&su[c2 * SUP + j];
            ((float4*)yrow)[e4] = v;
        }
    }
}

// ---------------------------------------------------------------------------
// GEMM 1: z = out_w(512x256) @ ys4 + out_b ; GLU ; + x residual  -> res
// ---------------------------------------------------------------------------
__global__ void gemm_glu_kernel(const float* __restrict__ X, const float* __restrict__ W,
                                const float* __restrict__ bias, const float* __restrict__ xres,
                                float* __restrict__ out) {
    __shared__ __align__(16) float Xs[32][68];
    __shared__ __align__(16) float W0s[32][68];
    __shared__ __align__(16) float W1s[32][68];
    int b = blockIdx.z;
    int l0 = blockIdx.x * 64;
    int c0 = blockIdx.y * 64;
    int t = threadIdx.x, tx = t & 15, ty = t >> 4;
    float acc0[4][4] = {}, acc1[4][4] = {};
    const float* Xb = X + (size_t)b * HH * LL;
    for (int k0 = 0; k0 < HH; k0 += 32) {
        #pragma unroll
        for (int i = 0; i < 8; ++i) {
            int idx = t + i * 256, k = idx >> 6, l = idx & 63;
            Xs[k][l] = Xb[(size_t)(k0 + k) * LL + l0 + l];
        }
        {
            int o = t >> 2, kk = (t & 3) * 8;
            const float* wp0 = W + (size_t)(c0 + o) * HH + k0 + kk;
            const float* wp1 = W + (size_t)(c0 + 256 + o) * HH + k0 + kk;
            #pragma unroll
            for (int j = 0; j < 8; ++j) { W0s[kk + j][o] = wp0[j]; W1s[kk + j][o] = wp1[j]; }
        }
        __syncthreads();
        #pragma unroll
        for (int k = 0; k < 32; ++k) {
            float4 xv = *(const float4*)&Xs[k][tx * 4];
            float4 w0 = *(const float4*)&W0s[k][ty * 4];
            float4 w1 = *(const float4*)&W1s[k][ty * 4];
            const float* xp = &xv.x; const float* p0 = &w0.x; const float* p1 = &w1.x;
            #pragma unroll
            for (int i = 0; i < 4; ++i)
                #pragma unroll
                for (int j = 0; j < 4; ++j) {
                    acc0[i][j] = fmaf(p0[i], xp[j], acc0[i][j]);
                    acc1[i][j] = fmaf(p1[i], xp[j], acc1[i][j]);
                }
        }
        __syncthreads();
    }
    #pragma unroll
    for (int i = 0; i < 4; ++i) {
        int c = c0 + ty * 4 + i;
        float b0 = bias[c], b1 = bias[c + 256];
        float4 xr = *(const float4*)&xres[((size_t)b * HH + c) * LL + l0 + tx * 4];
        float4 ov;
        #pragma unroll
        for (int j = 0; j < 4; ++j) {
            float z0 = acc0[i][j] + b0;
            float z1 = acc1[i][j] + b1;
            (&ov.x)[j] = z0 * sigmoid_(z1) + (&xr.x)[j];
        }
        *(float4*)&out[((size_t)b * HH + c) * LL + l0 + tx * 4] = ov;
    }
}

// Generic GEMM: out[b,o,l] = act(sum_k W[o,k] X[b,k,l] + bias[o]) (+resid)
template <int KV, int WLD, int ACT>
__global__ void gemm_kernel(const float* __restrict__ X, const float* __restrict__ W,
                            const float* bias, const float* resid,
                            float* out) {
    __shared__ __align__(16) float Xs[32][68];
    __shared__ __align__(16) float Ws[32][68];
    int b = blockIdx.z;
    int l0 = blockIdx.x * 64;
    int o0 = blockIdx.y * 64;
    int O = gridDim.y * 64;
    int t = threadIdx.x, tx = t & 15, ty = t >> 4;
    float acc[4][4] = {};
    const float* Xb = X + (size_t)b * KV * LL;
    for (int k0 = 0; k0 < KV; k0 += 32) {
        #pragma unroll
        for (int i = 0; i < 8; ++i) {
            int idx = t + i * 256, k = idx >> 6, l = idx & 63;
            Xs[k][l] = Xb[(size_t)(k0 + k) * LL + l0 + l];
        }
        {
            int o = t >> 2, kk = (t & 3) * 8;
            const float* wp = W + (size_t)(o0 + o) * WLD + k0 + kk;
            #pragma unroll
            for (int j = 0; j < 8; ++j) Ws[kk + j][o] = wp[j];
        }
        __syncthreads();
        #pragma unroll
        for (int k = 0; k < 32; ++k) {
            float4 xv = *(const float4*)&Xs[k][tx * 4];
            float4 wv = *(const float4*)&Ws[k][ty * 4];
            const float* xp = &xv.x; const float* wp = &wv.x;
            #pragma unroll
            for (int i = 0; i < 4; ++i)
                #pragma unroll
                for (int j = 0; j < 4; ++j)
                    acc[i][j] = fmaf(wp[i], xp[j], acc[i][j]);
        }
        __syncthreads();
    }
    #pragma unroll
    for (int i = 0; i < 4; ++i) {
        int o = o0 + ty * 4 + i;
        float bv = bias ? bias[o] : 0.f;
        float4 ov;
        if (ACT == 0) {
            float4 rv = *(const float4*)&resid[((size_t)b * O + o) * LL + l0 + tx * 4];
            #pragma unroll
            for (int j = 0; j < 4; ++j) (&ov.x)[j] = acc[i][j] + bv + (&rv.x)[j];
        } else {
            #pragma unroll
            for (int j = 0; j < 4; ++j) (&ov.x)[j] = gelu_tanh(acc[i][j] + bv);
        }
        *(float4*)&out[((size_t)b * O + o) * LL + l0 + tx * 4] = ov;
    }
}

// ---------------------------------------------------------------------------
extern "C" void kernel_launch(void* const* d_in, const int* in_sizes, int n_in,
                              void* d_out, int out_size, void* d_ws, size_t ws_size,
                              hipStream_t stream) {
    (void)in_sizes; (void)n_in; (void)out_size; (void)ws_size;
    const float* x      = (const float*)d_in[0];
    const float* emb    = (const float*)d_in[1];
    const float* fc_t_w = (const float*)d_in[2];
    const float* fc_t_b = (const float*)d_in[3];
    const float* log_dt = (const float*)d_in[4];
    const float* A_re   = (const float*)d_in[5];
    const float* A_im   = (const float*)d_in[6];
    const float* C_re   = (const float*)d_in[7];
    const float* C_im   = (const float*)d_in[8];
    const float* Dp     = (const float*)d_in[9];
    const float* out_w  = (const float*)d_in[10];
    const float* out_b  = (const float*)d_in[11];
    const float* n1_m   = (const float*)d_in[12];
    const float* n1_s   = (const float*)d_in[13];
    const float* n2_m   = (const float*)d_in[14];
    const float* n2_s   = (const float*)d_in[15];
    const float* ff_w1  = (const float*)d_in[16];
    const float* ff_b1  = (const float*)d_in[17];
    const float* ff_w2  = (const float*)d_in[18];
    const float* ff_b2  = (const float*)d_in[19];
    float* outp = (float*)d_out;

    // Workspace: 2*BHL floats = 128 MiB.
    //   region A [0, BHL):     u (TLN1 out) -> ys4 (scan, in place) -> t2 (TLN2 out)
    //   region B [BHL, 2*BHL): P params (dead after scan_fused), then FF h halves
    //   res lives in d_out; ff2 accumulates into d_out in place.
    float* wsf  = (float*)d_ws;
    float* u    = wsf;                      // region A
    float* regB = wsf + BHL;                // region B
    float* P    = regB;                     // params, dead before hbuf written
    float* hbuf = regB;                     // FF hidden half (B,256,L) = BHL floats

    setup_s4_params<<<16, 256, 0, stream>>>(log_dt, A_re, A_im, C_re, C_im, P);
    part_t_kernel<<<8, 256, 0, stream>>>(emb, fc_t_w, fc_t_b, P);

    // u = TLN1(x) + part_t
    tln_kernel<<<dim3(LL / 64, BB), 256, 0, stream>>>(x, u, n1_m, n1_s, P + OFF_PT);

    // ys4 = gelu(S4_bidir(u) + u*D)  -> in place over u
    scan_fused<<<BB * HH, 256, 0, stream>>>(u, P, Dp, u);

    // res = x + GLU(out_w @ ys4 + out_b)   -> d_out
    gemm_glu_kernel<<<dim3(LL / 64, 4, BB), 256, 0, stream>>>(u, out_w, out_b, x, outp);

    // t2 = TLN2(res)  (into region A, over dead ys4)
    tln_kernel<<<dim3(LL / 64, BB), 256, 0, stream>>>(outp, u, n2_m, n2_s, nullptr);

    // FF in two 256-channel halves (h half fits in region B):
    gemm_kernel<256, 256, 1><<<dim3(LL / 64, 4, BB), 256, 0, stream>>>(u, ff_w1, ff_b1, nullptr, hbuf);
    gemm_kernel<256, 512, 0><<<dim3(LL / 64, 4, BB), 256, 0, stream>>>(hbuf, ff_w2, ff_b2, outp, outp);
    gemm_kernel<256, 256, 1><<<dim3(LL / 64, 4, BB), 256, 0, stream>>>(u, ff_w1 + 256 * 256, ff_b1 + 256, nullptr, hbuf);
    gemm_kernel<256, 512, 0><<<dim3(LL / 64, 4, BB), 256, 0, stream>>>(hbuf, ff_w2 + 256, nullptr, outp, outp);
}

// Round 5
// 770.139 us; speedup vs baseline: 2.0027x; 1.5058x over previous
//
#include <hip/hip_runtime.h>
#include <hip/hip_bf16.h>
#include <math.h>

typedef unsigned short u16;
typedef float fx4 __attribute__((ext_vector_type(4)));
typedef __bf16 bx8 __attribute__((ext_vector_type(8)));

constexpr int BB  = 8;
constexpr int HH  = 256;
constexpr int LL  = 8192;
constexpr int NN  = 16;
constexpr int DTE = 512;
constexpr int SC  = 128;
constexpr int CHN = 64;
constexpr int HN  = HH * NN;

constexpr size_t BHL = (size_t)BB * HH * LL;

constexpr int OFF_WR  = 0;
constexpr int OFF_WI  = HN;
constexpr int OFF_WSR = 2 * HN;
constexpr int OFF_WSI = 3 * HN;
constexpr int OFF_C0R = 4 * HN;
constexpr int OFF_C0I = 5 * HN;
constexpr int OFF_C1R = 6 * HN;
constexpr int OFF_C1I = 7 * HN;
constexpr int OFF_PT  = 8 * HN;

__device__ __forceinline__ float gelu_tanh(float x) {
    float x3 = x * x * x;
    float y = 1.5957691216057308f * x + 0.07135481627767453f * x3;
    return x / (1.0f + __expf(-y));
}
__device__ __forceinline__ float sigmoid_(float x) {
    return 1.0f / (1.0f + __expf(-x));
}
__device__ __forceinline__ __hip_bfloat16 f2b(float x) { return __float2bfloat16(x); }
__device__ __forceinline__ float b2f(__hip_bfloat16 x) { return __bfloat162float(x); }
__device__ __forceinline__ u16 f2us(float x) {
    __hip_bfloat16 b = __float2bfloat16(x);
    return *reinterpret_cast<u16*>(&b);
}

__global__ void setup_s4_params(const float* __restrict__ log_dt,
                                const float* __restrict__ A_re,
                                const float* __restrict__ A_im,
                                const float* __restrict__ C_re,
                                const float* __restrict__ C_im,
                                float* __restrict__ P) {
    int idx = blockIdx.x * blockDim.x + threadIdx.x;
    if (idx >= HN) return;
    int h = idx >> 4;
    double dt = exp((double)log_dt[h]);
    double Ar = (double)A_re[idx], Ai = (double)A_im[idx];
    double dr = Ar * dt, di = Ai * dt;
    double e1 = exp(dr);
    double wr = e1 * cos(di), wi = e1 * sin(di);
    double eS = exp(dr * SC);
    double wSr = eS * cos(di * SC), wSi = eS * sin(di * SC);
    double d2 = Ar * Ar + Ai * Ai;
    double nr = wr - 1.0, ni = wi;
    double rr = (nr * Ar + ni * Ai) / d2;
    double ri = (ni * Ar - nr * Ai) / d2;
    double c0r = (double)C_re[idx],        c0i = (double)C_im[idx];
    double c1r = (double)C_re[HN + idx],   c1i = (double)C_im[HN + idx];
    P[OFF_WR  + idx] = (float)wr;
    P[OFF_WI  + idx] = (float)wi;
    P[OFF_WSR + idx] = (float)wSr;
    P[OFF_WSI + idx] = (float)wSi;
    P[OFF_C0R + idx] = (float)(2.0 * (c0r * rr - c0i * ri));
    P[OFF_C0I + idx] = (float)(2.0 * (c0r * ri + c0i * rr));
    P[OFF_C1R + idx] = (float)(2.0 * (c1r * rr - c1i * ri));
    P[OFF_C1I + idx] = (float)(2.0 * (c1r * ri + c1i * rr));
}

__global__ void part_t_kernel(const float* __restrict__ emb,
                              const float* __restrict__ w,
                              const float* __restrict__ bias,
                              float* __restrict__ P) {
    int idx = blockIdx.x * blockDim.x + threadIdx.x;
    if (idx >= BB * HH) return;
    int b = idx / HH, h = idx % HH;
    float s = bias[h];
    const float* er = emb + (size_t)b * DTE;
    const float* wr = w + (size_t)h * DTE;
    for (int e = 0; e < DTE; ++e) s = fmaf(er[e], wr[e], s);
    P[OFF_PT + idx] = s;
}

__global__ void convert_w_kernel(const float* __restrict__ src, u16* __restrict__ dst, int n) {
    int i = blockIdx.x * 256 + threadIdx.x;
    if (i < n) dst[i] = f2us(src[i]);
}

__global__ void tln_kernel(const float* __restrict__ in, float* __restrict__ out,
                           const float* __restrict__ mptr, const float* __restrict__ sptr,
                           const float* __restrict__ part_t) {
    int b = blockIdx.y;
    int l0 = blockIdx.x * 64;
    int t = threadIdx.x;
    int q = t >> 6, li = t & 63;
    const float* base = in + (size_t)b * HH * LL + l0 + li;
    float sum = 0.f, sq = 0.f;
    for (int i = 0; i < 64; ++i) {
        float v = base[(size_t)(q * 64 + i) * LL];
        sum += v; sq = fmaf(v, v, sq);
    }
    __shared__ float rs[4][64], rq[4][64], meanS[64], scaleS[64];
    rs[q][li] = sum; rq[q][li] = sq;
    __syncthreads();
    if (q == 0) {
        float s  = rs[0][li] + rs[1][li] + rs[2][li] + rs[3][li];
        float s2 = rq[0][li] + rq[1][li] + rq[2][li] + rq[3][li];
        float mean = s * (1.f / 256.f);
        float var  = fmaxf(s2 * (1.f / 256.f) - mean * mean, 0.f);
        meanS[li]  = mean;
        scaleS[li] = sptr[0] / sqrtf(var);
    }
    __syncthreads();
    float mean = meanS[li], scale = scaleS[li], m = mptr[0];
    float* ob = out + (size_t)b * HH * LL + l0 + li;
    for (int i = 0; i < 64; ++i) {
        int h = q * 64 + i;
        float v = base[(size_t)h * LL];
        float y = scale * (v - mean + m) + part_t[b * HH + h];
        ob[(size_t)h * LL] = y;
    }
}

__global__ void tln2t_kernel(const float* __restrict__ in, u16* __restrict__ outT,
                             const float* __restrict__ mptr, const float* __restrict__ sptr) {
    int b = blockIdx.y;
    int l0 = blockIdx.x * 64;
    int t = threadIdx.x;
    int q = t >> 6, li = t & 63;
    const float* base = in + (size_t)b * HH * LL + l0 + li;
    float sum = 0.f, sq = 0.f;
    for (int i = 0; i < 64; ++i) {
        float v = base[(size_t)(q * 64 + i) * LL];
        sum += v; sq = fmaf(v, v, sq);
    }
    __shared__ float rs[4][64], rq[4][64], meanS[64], scaleS[64];
    __shared__ u16 TT[64 * 262];
    rs[q][li] = sum; rq[q][li] = sq;
    __syncthreads();
    if (q == 0) {
        float s  = rs[0][li] + rs[1][li] + rs[2][li] + rs[3][li];
        float s2 = rq[0][li] + rq[1][li] + rq[2][li] + rq[3][li];
        float mean = s * (1.f / 256.f);
        float var  = fmaxf(s2 * (1.f / 256.f) - mean * mean, 0.f);
        meanS[li]  = mean;
        scaleS[li] = sptr[0] / sqrtf(var);
    }
    __syncthreads();
    float mean = meanS[li], scale = scaleS[li], m = mptr[0];
    for (int i = 0; i < 64; ++i) {
        int h = q * 64 + i;
        float v = base[(size_t)h * LL];
        TT[li * 262 + h] = f2us(scale * (v - mean + m));
    }
    __syncthreads();
    #pragma unroll
    for (int i = 0; i < 32; ++i) {
        int idx = t + i * 256;
        int c = idx & 127, l = idx >> 7;
        unsigned int v = *(const unsigned int*)&TT[l * 262 + 2 * c];
        *(unsigned int*)&outT[((size_t)b * LL + l0 + l) * 256 + 2 * c] = v;
    }
}

constexpr int SUP  = 132;
constexpr int FINP = 130;

__global__ __launch_bounds__(256, 2) void scan_fused(
    const float* __restrict__ uIn, const float* __restrict__ P,
    const float* __restrict__ Dp, float* __restrict__ ys)
{
    __shared__ float          su[64 * SUP];
    __shared__ __hip_bfloat16 ybuf[64 * SUP];
    __shared__ __hip_bfloat16 fin[2 * NN * FINP];

    const int bh  = blockIdx.x;
    const int h   = bh & (HH - 1);
    const int tid = threadIdx.x;
    const float* urow = uIn + (size_t)bh * LL;
    float* yrow = ys + (size_t)bh * LL;

    {
        const float4* u4 = (const float4*)urow;
        #pragma unroll
        for (int i = 0; i < 8; ++i) {
            int e4 = tid + i * 256;
            float4 v = u4[e4];
            int g = e4 << 2;
            int c = g >> 7, j = g & 127;
            *(float4*)&su[c * SUP + j] = v;
        }
    }
    __syncthreads();

    {
        const int c   = tid & 63;
        const int dir = (tid >> 6) & 1;
        const int nb  = (tid >> 7) * 8;
        float wr8[8], wi8[8], fr[8], fi[8];
        #pragma unroll
        for (int k = 0; k < 8; ++k) {
            wr8[k] = P[OFF_WR + h * NN + nb + k];
            wi8[k] = P[OFF_WI + h * NN + nb + k];
            fr[k] = 0.f; fi[k] = 0.f;
        }
        const float* sc = &su[c * SUP];
        if (dir == 0) {
            for (int j = 0; j < 128; ++j) {
                float uv = sc[j];
                #pragma unroll
                for (int k = 0; k < 8; ++k) {
                    float nr = fmaf(wr8[k], fr[k], fmaf(-wi8[k], fi[k], uv));
                    float ni = fmaf(wr8[k], fi[k], wi8[k] * fr[k]);
                    fr[k] = nr; fi[k] = ni;
                }
            }
        } else {
            for (int j = 127; j >= 0; --j) {
                float uv = sc[j];
                #pragma unroll
                for (int k = 0; k < 8; ++k) {
                    float nr = fmaf(wr8[k], fr[k], fmaf(-wi8[k], fi[k], uv));
                    float ni = fmaf(wr8[k], fi[k], wi8[k] * fr[k]);
                    fr[k] = nr; fi[k] = ni;
                }
            }
        }
        #pragma unroll
        for (int k = 0; k < 8; ++k) {
            int n = nb + k;
            __hip_bfloat16* fp = &fin[(dir * NN + n) * FINP + 2 * c];
            fp[0] = f2b(fr[k]); fp[1] = f2b(fi[k]);
        }
    }
    __syncthreads();

    if (tid < 32) {
        const int dir = tid >> 4, n = tid & 15;
        float wSr = P[OFF_WSR + h * NN + n], wSi = P[OFF_WSI + h * NN + n];
        __hip_bfloat16* fb = &fin[(dir * NN + n) * FINP];
        float cr = 0.f, ci = 0.f;
        if (dir == 0) {
            for (int c = 0; c < CHN; ++c) {
                float fr = b2f(fb[2 * c]), fi = b2f(fb[2 * c + 1]);
                fb[2 * c] = f2b(cr); fb[2 * c + 1] = f2b(ci);
                float nr = fmaf(wSr, cr, fmaf(-wSi, ci, fr));
                float ni = fmaf(wSr, ci, fmaf(wSi, cr, fi));
                cr = nr; ci = ni;
            }
        } else {
            for (int c = CHN - 1; c >= 0; --c) {
                float fr = b2f(fb[2 * c]), fi = b2f(fb[2 * c + 1]);
                fb[2 * c] = f2b(cr); fb[2 * c + 1] = f2b(ci);
                float nr = fmaf(wSr, cr, fmaf(-wSi, ci, fr));
                float ni = fmaf(wSr, ci, fmaf(wSi, cr, fi));
                cr = nr; ci = ni;
            }
        }
    }
    __syncthreads();

    float wr[NN], wi[NN], cr[NN], ci[NN], sr[NN], si[NN];
    float ucur = 0.f;
    const int role = (tid >> 6) & 1;
    const int c = tid & 63;
    float* sc = &su[c * SUP];
    __hip_bfloat16* yc = &ybuf[c * SUP];
    const float Dh = Dp[h];

    if (tid < 128) {
        const int cO = role ? OFF_C1R : OFF_C0R;
        const int cI = role ? OFF_C1I : OFF_C0I;
        #pragma unroll
        for (int n = 0; n < NN; ++n) {
            wr[n] = P[OFF_WR + h * NN + n]; wi[n] = P[OFF_WI + h * NN + n];
            cr[n] = P[cO + h * NN + n];     ci[n] = P[cI + h * NN + n];
            const __hip_bfloat16* fp = &fin[(role * NN + n) * FINP + 2 * c];
            sr[n] = b2f(fp[0]); si[n] = b2f(fp[1]);
        }
        if (role == 0) {
            for (int j = 0; j < 64; ++j) {
                float uv = sc[j];
                float acc = 0.f;
                #pragma unroll
                for (int n = 0; n < NN; ++n) {
                    float nr = fmaf(wr[n], sr[n], fmaf(-wi[n], si[n], uv));
                    float ni = fmaf(wr[n], si[n], wi[n] * sr[n]);
                    sr[n] = nr; si[n] = ni;
                    acc = fmaf(cr[n], nr, fmaf(-ci[n], ni, acc));
                }
                yc[j] = f2b(acc);
            }
        } else {
            {
                float acc = 0.f;
                #pragma unroll
                for (int n = 0; n < NN; ++n)
                    acc = fmaf(cr[n], sr[n], fmaf(-ci[n], si[n], acc));
                yc[127] = f2b(acc);
            }
            for (int t = 127; t >= 65; --t) {
                float uv = sc[t];
                float acc = 0.f;
                #pragma unroll
                for (int n = 0; n < NN; ++n) {
                    float nr = fmaf(wr[n], sr[n], fmaf(-wi[n], si[n], uv));
                    float ni = fmaf(wr[n], si[n], wi[n] * sr[n]);
                    sr[n] = nr; si[n] = ni;
                    acc = fmaf(cr[n], nr, fmaf(-ci[n], ni, acc));
                }
                yc[t - 1] = f2b(acc);
            }
            ucur = sc[64];
        }
    }
    __syncthreads();
    if (tid < 128) {
        if (role == 0) {
            for (int j = 64; j < 128; ++j) {
                float uv = sc[j];
                float acc = 0.f;
                #pragma unroll
                for (int n = 0; n < NN; ++n) {
                    float nr = fmaf(wr[n], sr[n], fmaf(-wi[n], si[n], uv));
                    float ni = fmaf(wr[n], si[n], wi[n] * sr[n]);
                    sr[n] = nr; si[n] = ni;
                    acc = fmaf(cr[n], nr, fmaf(-ci[n], ni, acc));
                }
                float tot = acc + b2f(yc[j]) + uv * Dh;
                sc[j] = gelu_tanh(tot);
            }
        } else {
            for (int t = 64; t >= 1; --t) {
                float acc = 0.f;
                #pragma unroll
                for (int n = 0; n < NN; ++n) {
                    float nr = fmaf(wr[n], sr[n], fmaf(-wi[n], si[n], ucur));
                    float ni = fmaf(wr[n], si[n], wi[n] * sr[n]);
                    sr[n] = nr; si[n] = ni;
                    acc = fmaf(cr[n], nr, fmaf(-ci[n], ni, acc));
                }
                float un = sc[t - 1];
                float tot = acc + b2f(yc[t - 1]) + un * Dh;
                sc[t - 1] = gelu_tanh(tot);
                ucur = un;
            }
        }
    }
    __syncthreads();

    {
        #pragma unroll
        for (int i = 0; i < 8; ++i) {
            int e4 = tid + i * 256;
            int g = e4 << 2;
            int c2 = g >> 7, j = g & 127;
            float4 v = *(const float4*)&su[c2 * SUP + j];
            ((float4*)yrow)[e4] = v;
        }
    }
}

__global__ void gemm_glu_kernel(const float* __restrict__ X, const float* __restrict__ W,
                                const float* __restrict__ bias, const float* __restrict__ xres,
                                float* __restrict__ out) {
    __shared__ __align__(16) float Xs[32][68];
    __shared__ __align__(16) float W0s[32][68];
    __shared__ __align__(16) float W1s[32][68];
    int b = blockIdx.z;
    int l0 = blockIdx.x * 64;
    int c0 = blockIdx.y * 64;
    int t = threadIdx.x, tx = t & 15, ty = t >> 4;
    float acc0[4][4] = {}, acc1[4][4] = {};
    const float* Xb = X + (size_t)b * HH * LL;
    for (int k0 = 0; k0 < HH; k0 += 32) {
        #pragma unroll
        for (int i = 0; i < 8; ++i) {
            int idx = t + i * 256, k = idx >> 6, l = idx & 63;
            Xs[k][l] = Xb[(size_t)(k0 + k) * LL + l0 + l];
        }
        {
            int o = t >> 2, kk = (t & 3) * 8;
            const float* wp0 = W + (size_t)(c0 + o) * HH + k0 + kk;
            const float* wp1 = W + (size_t)(c0 + 256 + o) * HH + k0 + kk;
            #pragma unroll
            for (int j = 0; j < 8; ++j) { W0s[kk + j][o] = wp0[j]; W1s[kk + j][o] = wp1[j]; }
        }
        __syncthreads();
        #pragma unroll
        for (int k = 0; k < 32; ++k) {
            float4 xv = *(const float4*)&Xs[k][tx * 4];
            float4 w0 = *(const float4*)&W0s[k][ty * 4];
            float4 w1 = *(const float4*)&W1s[k][ty * 4];
            const float* xp = &xv.x; const float* p0 = &w0.x; const float* p1 = &w1.x;
            #pragma unroll
            for (int i = 0; i < 4; ++i)
                #pragma unroll
                for (int j = 0; j < 4; ++j) {
                    acc0[i][j] = fmaf(p0[i], xp[j], acc0[i][j]);
                    acc1[i][j] = fmaf(p1[i], xp[j], acc1[i][j]);
                }
        }
        __syncthreads();
    }
    #pragma unroll
    for (int i = 0; i < 4; ++i) {
        int c = c0 + ty * 4 + i;
        float b0 = bias[c], b1 = bias[c + 256];
        float4 xr = *(const float4*)&xres[((size_t)b * HH + c) * LL + l0 + tx * 4];
        float4 ov;
        #pragma unroll
        for (int j = 0; j < 4; ++j) {
            float z0 = acc0[i][j] + b0;
            float z1 = acc1[i][j] + b1;
            (&ov.x)[j] = z0 * sigmoid_(z1) + (&xr.x)[j];
        }
        *(float4*)&out[((size_t)b * HH + c) * LL + l0 + tx * 4] = ov;
    }
}

template<int MODE, int WLD>
__global__ __launch_bounds__(256, 3) void gemm_mfma(
    const u16* __restrict__ Aw, const u16* __restrict__ Bm,
    const float* bias, const float* resid, void* outv)
{
    __shared__ __align__(16) char smem[33792];
    u16*   Alds = (u16*)smem;
    u16*   Blds = (u16*)(smem + 16384);
    float* Eps  = (float*)smem;
    u16*   TT   = (u16*)smem;

    const int tid  = threadIdx.x;
    const int lane = tid & 63;
    const int wv   = tid >> 6;
    const int wr   = wv >> 1, wc = wv & 1;
    const int bz   = blockIdx.z;
    const int l0   = blockIdx.x * 128;
    const int mbase = blockIdx.y * 128;

    fx4 acc[4][4];
    #pragma unroll
    for (int i = 0; i < 4; ++i)
        #pragma unroll
        for (int j = 0; j < 4; ++j) {
            fx4 z = {0.f, 0.f, 0.f, 0.f};
            acc[i][j] = z;
        }

    const size_t brow0 = (size_t)bz * LL;
    for (int k0 = 0; k0 < 256; k0 += 64) {
        #pragma unroll
        for (int i = 0; i < 4; ++i) {
            int f = tid + i * 256;
            int mm = f & 15, kg = (f >> 4) & 3, m16 = (f >> 6) & 7, ks = f >> 9;
            int k = k0 + ks * 32 + kg * 8;
            int o = mbase + m16 * 16 + mm;
            int4 wv4 = *(const int4*)(Aw + (size_t)o * WLD + k);
            *(int4*)&Alds[f * 8] = wv4;
            int row = l0 + m16 * 16 + mm;
            int4 xv4 = *(const int4*)(Bm + (brow0 + row) * 256 + k);
            *(int4*)&Blds[f * 8] = xv4;
        }
        __syncthreads();
        #pragma unroll
        for (int ks = 0; ks < 2; ++ks) {
            bx8 av[4], bv[4];
            #pragma unroll
            for (int mt = 0; mt < 4; ++mt)
                av[mt] = *(const bx8*)&Alds[(ks * 512 + (wr * 4 + mt) * 64 + lane) * 8];
            #pragma unroll
            for (int nt = 0; nt < 4; ++nt)
                bv[nt] = *(const bx8*)&Blds[(ks * 512 + (wc * 4 + nt) * 64 + lane) * 8];
            #pragma unroll
            for (int mt = 0; mt < 4; ++mt)
                #pragma unroll
                for (int nt = 0; nt < 4; ++nt)
                    acc[mt][nt] = __builtin_amdgcn_mfma_f32_16x16x32_bf16(
                        av[mt], bv[nt], acc[mt][nt], 0, 0, 0);
        }
        __syncthreads();
    }

    if (MODE == 1) {
        u16* hT = (u16*)outv;
        #pragma unroll
        for (int p = 0; p < 2; ++p) {
            if (p) __syncthreads();
            if (wc == p) {
                #pragma unroll
                for (int mt = 0; mt < 4; ++mt) {
                    int mb = wr * 64 + mt * 16 + (lane >> 4) * 4;
                    float bvv[4];
                    #pragma unroll
                    for (int r = 0; r < 4; ++r) bvv[r] = bias[mbase + mb + r];
                    #pragma unroll
                    for (int nt = 0; nt < 4; ++nt) {
                        int n = nt * 16 + (lane & 15);
                        u16 pk[4];
                        #pragma unroll
                        for (int r = 0; r < 4; ++r)
                            pk[r] = f2us(gelu_tanh(acc[mt][nt][r] + bvv[r]));
                        *(ushort4*)&TT[n * 136 + mb] = *(const ushort4*)pk;
                    }
                }
            }
            __syncthreads();
            #pragma unroll
            for (int i = 0; i < 4; ++i) {
                int idx = tid + i * 256;
                int l = idx >> 4, c = idx & 15;
                int4 v = *(const int4*)&TT[l * 136 + c * 8];
                *(int4*)&hT[((size_t)bz * LL + l0 + p * 64 + l) * 256 + mbase + c * 8] = v;
            }
        }
    } else {
        float* outp = (float*)outv;
        #pragma unroll
        for (int p = 0; p < 2; ++p) {
            if (p) __syncthreads();
            if (wc == p) {
                #pragma unroll
                for (int mt = 0; mt < 4; ++mt)
                    #pragma unroll
                    for (int nt = 0; nt < 4; ++nt) {
                        int m = wr * 64 + mt * 16 + (lane >> 4) * 4;
                        int n = nt * 16 + (lane & 15);
                        #pragma unroll
                        for (int r = 0; r < 4; ++r)
                            Eps[(m + r) * 66 + n] = acc[mt][nt][r];
                    }
            }
            __syncthreads();
            #pragma unroll
            for (int i = 0; i < 8; ++i) {
                int idx = tid + i * 256;
                int r = idx >> 4, lq = idx & 15;
                float bv = bias ? bias[mbase + r] : 0.f;
                size_t ga = ((size_t)bz * HH + mbase + r) * LL + l0 + p * 64 + lq * 4;
                float4 rv = *(const float4*)&resid[ga];
                float4 ov;
                #pragma unroll
                for (int j = 0; j < 4; ++j)
                    (&ov.x)[j] = Eps[r * 66 + lq * 4 + j] + bv + (&rv.x)[j];
                *(float4*)&outp[ga] = ov;
            }
        }
    }
}

extern "C" void kernel_launch(void* const* d_in, const int* in_sizes, int n_in,
                              void* d_out, int out_size, void* d_ws, size_t ws_size,
                              hipStream_t stream) {
    (void)in_sizes; (void)n_in; (void)out_size; (void)ws_size;
    const float* x      = (const float*)d_in[0];
    const float* emb    = (const float*)d_in[1];
    const float* fc_t_w = (const float*)d_in[2];
    const float* fc_t_b = (const float*)d_in[3];
    const float* log_dt = (const float*)d_in[4];
    const float* A_re   = (const float*)d_in[5];
    const float* A_im   = (const float*)d_in[6];
    const float* C_re   = (const float*)d_in[7];
    const float* C_im   = (const float*)d_in[8];
    const float* Dp     = (const float*)d_in[9];
    const float* out_w  = (const float*)d_in[10];
    const float* out_b  = (const float*)d_in[11];
    const float* n1_m   = (const float*)d_in[12];
    const float* n1_s   = (const float*)d_in[13];
    const float* n2_m   = (const float*)d_in[14];
    const float* n2_s   = (const float*)d_in[15];
    const float* ff_w1  = (const float*)d_in[16];
    const float* ff_b1  = (const float*)d_in[17];
    const float* ff_w2  = (const float*)d_in[18];
    const float* ff_b2  = (const float*)d_in[19];
    float* outp = (float*)d_out;

    // Workspace map (floats, total 2*BHL = 128 MiB):
    //   region A [0, BHL):         u fp32 -> ys4 (scan in place) -> t2T bf16
    //   region B [BHL, 1.5*BHL):   hT bf16 half (B,8192,256)
    //   WP corner [2*BHL-512K floats, ...): bf16 weights (W1c, W2c) + P
    float* wsf  = (float*)d_ws;
    float* u    = wsf;
    u16*   t2T  = (u16*)wsf;
    u16*   hT   = (u16*)(wsf + BHL);
    constexpr size_t WPOFF = 2 * BHL - 524288;
    u16*   W1c  = (u16*)(wsf + WPOFF);              // 512*256 bf16
    u16*   W2c  = W1c + 131072;                     // 256*512 bf16
    float* P    = wsf + WPOFF + 131072;             // 34,816 floats

    setup_s4_params<<<16, 256, 0, stream>>>(log_dt, A_re, A_im, C_re, C_im, P);
    part_t_kernel<<<8, 256, 0, stream>>>(emb, fc_t_w, fc_t_b, P);
    convert_w_kernel<<<512, 256, 0, stream>>>(ff_w1, W1c, 512 * 256);
    convert_w_kernel<<<512, 256, 0, stream>>>(ff_w2, W2c, 256 * 512);

    // u = TLN1(x) + part_t
    tln_kernel<<<dim3(LL / 64, BB), 256, 0, stream>>>(x, u, n1_m, n1_s, P + OFF_PT);

    // ys4 = gelu(S4_bidir(u) + u*D), in place over u
    scan_fused<<<BB * HH, 256, 0, stream>>>(u, P, Dp, u);

    // res = x + GLU(out_w @ ys4 + out_b)  -> d_out   (fp32: sigmoid-sensitive)
    gemm_glu_kernel<<<dim3(LL / 64, 4, BB), 256, 0, stream>>>(u, out_w, out_b, x, outp);

    // t2T = TLN2(res) transposed bf16
    tln2t_kernel<<<dim3(LL / 64, BB), 256, 0, stream>>>(outp, t2T, n2_m, n2_s);

    // FF in two hidden halves; hT half = 32 MB in region B
    gemm_mfma<1, 256><<<dim3(LL / 128, 2, BB), 256, 0, stream>>>(W1c, t2T, ff_b1, nullptr, hT);
    gemm_mfma<2, 512><<<dim3(LL / 128, 2, BB), 256, 0, stream>>>(W2c, hT, ff_b2, outp, outp);
    gemm_mfma<1, 256><<<dim3(LL / 128, 2, BB), 256, 0, stream>>>(W1c + 65536, t2T, ff_b1 + 256, nullptr, hT);
    gemm_mfma<2, 512><<<dim3(LL / 128, 2, BB), 256, 0, stream>>>(W2c + 256, hT, nullptr, outp, outp);
}